// Round 1
// baseline (573.256 us; speedup 1.0000x reference)
//
#include <hip/hip_runtime.h>

#define S 2048
#define DM 512
#define NH 8
#define HD 64
#define NB 2
#define BH (NB * NH)
#define MROWS (NB * S) // 4096

typedef __bf16 bf16x8 __attribute__((ext_vector_type(8)));
typedef float f32x4 __attribute__((ext_vector_type(4)));

union FragU {
  uint4 u;
  bf16x8 v;
  unsigned short s[8];
};

__device__ __forceinline__ unsigned short f2bf(float x) {
  unsigned u = __float_as_uint(x);
  u += 0x7FFFu + ((u >> 16) & 1u); // RNE
  return (unsigned short)(u >> 16);
}

// ---------------- weight transpose + bf16 convert: Wt[i][n][k] = W_i[k][n] ---
__global__ void k_wtrans(const float* __restrict__ w0, const float* __restrict__ w1,
                         const float* __restrict__ w2, const float* __restrict__ w3,
                         unsigned short* __restrict__ wt) {
  __shared__ float tile[64][65];
  int i = blockIdx.z;
  const float* w = (i == 0) ? w0 : (i == 1) ? w1 : (i == 2) ? w2 : w3;
  int k0 = blockIdx.x * 64;
  int n0 = blockIdx.y * 64;
  int tx = threadIdx.x, ty = threadIdx.y; // (64,4)
  for (int r = ty; r < 64; r += 4)
    tile[r][tx] = w[(size_t)(k0 + r) * DM + n0 + tx];
  __syncthreads();
  unsigned short* o = wt + (size_t)i * DM * DM;
  for (int r = ty; r < 64; r += 4)
    o[(size_t)(n0 + r) * DM + k0 + tx] = f2bf(tile[tx][r]);
}

// ---------------- QKV projection: out_bf16[b][h][s][d] = in @ W + bias -------
__global__ __launch_bounds__(256) void k_proj(
    const float* __restrict__ inq, const float* __restrict__ ink, const float* __restrict__ inv,
    const unsigned short* __restrict__ wt,
    const float* __restrict__ bq, const float* __restrict__ bk, const float* __restrict__ bv,
    unsigned short* __restrict__ oq, unsigned short* __restrict__ ok, unsigned short* __restrict__ ov) {
  int which = blockIdx.z;
  const float* in = (which == 0) ? inq : (which == 1) ? ink : inv;
  const float* bias = (which == 0) ? bq : (which == 1) ? bk : bv;
  unsigned short* out = (which == 0) ? oq : (which == 1) ? ok : ov;
  const unsigned short* w = wt + (size_t)which * DM * DM;

  int lane = threadIdx.x & 63, wv = threadIdx.x >> 6;
  int m0 = blockIdx.x * 64 + wv * 16;
  int n0 = blockIdx.y * 64;
  int kf = (lane >> 4) * 8;
  int arow = m0 + (lane & 15);

  f32x4 acc[4] = {{0.f, 0.f, 0.f, 0.f}, {0.f, 0.f, 0.f, 0.f},
                  {0.f, 0.f, 0.f, 0.f}, {0.f, 0.f, 0.f, 0.f}};

  for (int kk0 = 0; kk0 < DM; kk0 += 32) {
    const float* ap = in + (size_t)arow * DM + kk0 + kf;
    float4 a0 = *(const float4*)ap;
    float4 a1 = *(const float4*)(ap + 4);
    FragU af;
    af.s[0] = f2bf(a0.x); af.s[1] = f2bf(a0.y); af.s[2] = f2bf(a0.z); af.s[3] = f2bf(a0.w);
    af.s[4] = f2bf(a1.x); af.s[5] = f2bf(a1.y); af.s[6] = f2bf(a1.z); af.s[7] = f2bf(a1.w);
#pragma unroll
    for (int nt = 0; nt < 4; nt++) {
      FragU bfr;
      bfr.u = *(const uint4*)(w + (size_t)(n0 + nt * 16 + (lane & 15)) * DM + kk0 + kf);
      acc[nt] = __builtin_amdgcn_mfma_f32_16x16x32_bf16(af.v, bfr.v, acc[nt], 0, 0, 0);
    }
  }
#pragma unroll
  for (int nt = 0; nt < 4; nt++) {
#pragma unroll
    for (int r = 0; r < 4; r++) {
      int row = m0 + (lane >> 4) * 4 + r;   // b*S + s
      int col = n0 + nt * 16 + (lane & 15); // h*64 + d
      float val = acc[nt][r] + bias[col];
      int b = row >> 11, sIdx = row & (S - 1);
      int h = col >> 6, d = col & 63;
      out[(((size_t)(b * NH + h) * S) + sIdx) * HD + d] = f2bf(val);
    }
  }
}

// ---------------- V transpose: vvT[bh][d][s] = vstd[bh][s][d] ----------------
__global__ void k_vtrans(const unsigned short* __restrict__ vin, unsigned short* __restrict__ vout) {
  __shared__ unsigned short tile[64][65];
  int bh = blockIdx.y;
  int s0 = blockIdx.x * 64;
  int tx = threadIdx.x, ty = threadIdx.y; // (64,4)
  const unsigned short* ip = vin + (size_t)bh * S * HD;
  for (int r = ty; r < 64; r += 4)
    tile[r][tx] = ip[(size_t)(s0 + r) * HD + tx];
  __syncthreads();
  unsigned short* op = vout + (size_t)bh * S * HD;
  for (int r = ty; r < 64; r += 4)
    op[(size_t)r * S + s0 + tx] = tile[tx][r];
}

// ---------------- pass 1: invZ[bh][k] = 1 / sum_q exp(logit) (masked -> 0) ---
__global__ __launch_bounds__(256) void k_softmax_z(
    const unsigned short* __restrict__ qq, const unsigned short* __restrict__ kk,
    const int* __restrict__ mask, float* __restrict__ invZ) {
  int lane = threadIdx.x & 63, w = threadIdx.x >> 6;
  int bh = blockIdx.y;
  int b = bh >> 3;
  int k0 = blockIdx.x * 64 + w * 16;
  int kf = (lane >> 4) * 8;

  const unsigned short* kbase = kk + ((size_t)bh * S + k0 + (lane & 15)) * HD + kf;
  FragU a0, a1;
  a0.u = *(const uint4*)kbase;
  a1.u = *(const uint4*)(kbase + 32);

  const unsigned short* qbase = qq + (size_t)bh * S * HD;
  const int* mrow = mask + (size_t)b * S * S;

  float sum[4] = {0.f, 0.f, 0.f, 0.f};

  for (int q0 = 0; q0 < S; q0 += 64) {
#pragma unroll
    for (int nt = 0; nt < 4; nt++) {
      int qcol = q0 + nt * 16 + (lane & 15);
      const unsigned short* qp = qbase + (size_t)qcol * HD + kf;
      FragU b0, b1;
      b0.u = *(const uint4*)qp;
      b1.u = *(const uint4*)(qp + 32);
      f32x4 c = {0.f, 0.f, 0.f, 0.f};
      c = __builtin_amdgcn_mfma_f32_16x16x32_bf16(a0.v, b0.v, c, 0, 0, 0);
      c = __builtin_amdgcn_mfma_f32_16x16x32_bf16(a1.v, b1.v, c, 0, 0, 0);
#pragma unroll
      for (int r = 0; r < 4; r++) {
        int krow = k0 + (lane >> 4) * 4 + r;
        int msk = mrow[(size_t)krow * S + qcol];
        float e = __expf(c[r] * 0.125f);
        sum[r] += msk ? 0.f : e;
      }
    }
  }
#pragma unroll
  for (int r = 0; r < 4; r++) {
    float s = sum[r];
    s += __shfl_xor(s, 1);
    s += __shfl_xor(s, 2);
    s += __shfl_xor(s, 4);
    s += __shfl_xor(s, 8);
    if ((lane & 15) == 0)
      invZ[(size_t)bh * S + k0 + (lane >> 4) * 4 + r] = 1.0f / s;
  }
}

// ---------------- pass 2: attn write + O = A^T V -----------------------------
__global__ __launch_bounds__(256) void k_attn(
    const unsigned short* __restrict__ qq, const unsigned short* __restrict__ kk,
    const unsigned short* __restrict__ vvT, const int* __restrict__ mask,
    const float* __restrict__ invZ, float* __restrict__ attn_out,
    unsigned short* __restrict__ concat) {
  __shared__ __align__(16) unsigned short pT[64][72]; // [q_local][k_local], row=144B (16B aligned)
  int lane = threadIdx.x & 63, w = threadIdx.x >> 6;
  int bh = blockIdx.y;
  int b = bh >> 3, h = bh & 7;
  int q0 = blockIdx.x * 64;
  int kf = (lane >> 4) * 8;

  // resident Q B-frags (reused for every k-tile)
  FragU bq[4][2];
#pragma unroll
  for (int nt = 0; nt < 4; nt++) {
    const unsigned short* qp = qq + ((size_t)bh * S + q0 + nt * 16 + (lane & 15)) * HD + kf;
    bq[nt][0].u = *(const uint4*)qp;
    bq[nt][1].u = *(const uint4*)(qp + 32);
  }

  f32x4 o[4] = {{0.f, 0.f, 0.f, 0.f}, {0.f, 0.f, 0.f, 0.f},
                {0.f, 0.f, 0.f, 0.f}, {0.f, 0.f, 0.f, 0.f}};

  const unsigned short* kkb = kk + (size_t)bh * S * HD;
  const unsigned short* vb = vvT + (size_t)bh * HD * S;
  const int* mrow = mask + (size_t)b * S * S;
  float* ao = attn_out + (size_t)bh * S * S;
  const float* izb = invZ + (size_t)bh * S;

  for (int k0 = 0; k0 < S; k0 += 64) {
    int kw = k0 + w * 16;
    const unsigned short* kp = kkb + (size_t)(kw + (lane & 15)) * HD + kf;
    FragU a0, a1;
    a0.u = *(const uint4*)kp;
    a1.u = *(const uint4*)(kp + 32);
    float iz[4];
#pragma unroll
    for (int r = 0; r < 4; r++) iz[r] = izb[kw + (lane >> 4) * 4 + r];

#pragma unroll
    for (int nt = 0; nt < 4; nt++) {
      f32x4 c = {0.f, 0.f, 0.f, 0.f};
      c = __builtin_amdgcn_mfma_f32_16x16x32_bf16(a0.v, bq[nt][0].v, c, 0, 0, 0);
      c = __builtin_amdgcn_mfma_f32_16x16x32_bf16(a1.v, bq[nt][1].v, c, 0, 0, 0);
      int ql = nt * 16 + (lane & 15);
      int qcol = q0 + ql;
#pragma unroll
      for (int r = 0; r < 4; r++) {
        int kl = w * 16 + (lane >> 4) * 4 + r;
        int krow = k0 + kl;
        int msk = mrow[(size_t)krow * S + qcol];
        float a = msk ? 0.f : __expf(c[r] * 0.125f) * iz[r];
        ao[(size_t)krow * S + qcol] = a;
        pT[ql][kl] = f2bf(a);
      }
    }
    __syncthreads();

    // O[q][d] += P^T-tile @ V-tile
#pragma unroll
    for (int ks = 0; ks < 2; ks++) {
      FragU af;
      af.u = *(const uint4*)(&pT[w * 16 + (lane & 15)][kf + ks * 32]);
#pragma unroll
      for (int nt = 0; nt < 4; nt++) {
        FragU bfr;
        bfr.u = *(const uint4*)(vb + (size_t)(nt * 16 + (lane & 15)) * S + k0 + kf + ks * 32);
        o[nt] = __builtin_amdgcn_mfma_f32_16x16x32_bf16(af.v, bfr.v, o[nt], 0, 0, 0);
      }
    }
    __syncthreads();
  }

#pragma unroll
  for (int nt = 0; nt < 4; nt++) {
#pragma unroll
    for (int r = 0; r < 4; r++) {
      int qg = q0 + w * 16 + (lane >> 4) * 4 + r;
      int col = h * 64 + nt * 16 + (lane & 15);
      concat[((size_t)b * S + qg) * DM + col] = f2bf(o[nt][r]);
    }
  }
}

// ---------------- out projection: out = concat @ Wo + bo ---------------------
__global__ __launch_bounds__(256) void k_outproj(
    const unsigned short* __restrict__ concat, const unsigned short* __restrict__ wt,
    const float* __restrict__ bias, float* __restrict__ out) {
  const unsigned short* w = wt + (size_t)3 * DM * DM;
  int lane = threadIdx.x & 63, wv = threadIdx.x >> 6;
  int m0 = blockIdx.x * 64 + wv * 16;
  int n0 = blockIdx.y * 64;
  int kf = (lane >> 4) * 8;

  f32x4 acc[4] = {{0.f, 0.f, 0.f, 0.f}, {0.f, 0.f, 0.f, 0.f},
                  {0.f, 0.f, 0.f, 0.f}, {0.f, 0.f, 0.f, 0.f}};

  for (int kk0 = 0; kk0 < DM; kk0 += 32) {
    FragU af;
    af.u = *(const uint4*)(concat + (size_t)(m0 + (lane & 15)) * DM + kk0 + kf);
#pragma unroll
    for (int nt = 0; nt < 4; nt++) {
      FragU bfr;
      bfr.u = *(const uint4*)(w + (size_t)(n0 + nt * 16 + (lane & 15)) * DM + kk0 + kf);
      acc[nt] = __builtin_amdgcn_mfma_f32_16x16x32_bf16(af.v, bfr.v, acc[nt], 0, 0, 0);
    }
  }
#pragma unroll
  for (int nt = 0; nt < 4; nt++) {
#pragma unroll
    for (int r = 0; r < 4; r++) {
      int row = m0 + (lane >> 4) * 4 + r;
      int col = n0 + nt * 16 + (lane & 15);
      out[(size_t)row * DM + col] = acc[nt][r] + bias[col];
    }
  }
}

extern "C" void kernel_launch(void* const* d_in, const int* in_sizes, int n_in,
                              void* d_out, int out_size, void* d_ws, size_t ws_size,
                              hipStream_t stream) {
  (void)in_sizes; (void)n_in; (void)out_size; (void)ws_size;
  const float* v    = (const float*)d_in[0];
  const float* q    = (const float*)d_in[1];
  const float* k    = (const float*)d_in[2];
  const int*   mask = (const int*)d_in[3];
  const float* wq_w = (const float*)d_in[4];
  const float* wq_b = (const float*)d_in[5];
  const float* wk_w = (const float*)d_in[6];
  const float* wk_b = (const float*)d_in[7];
  const float* wv_w = (const float*)d_in[8];
  const float* wv_b = (const float*)d_in[9];
  const float* wo_w = (const float*)d_in[10];
  const float* wo_b = (const float*)d_in[11];

  char* ws = (char*)d_ws;
  size_t off = 0;
  auto alloc = [&](size_t bytes) {
    char* p = ws + off;
    off += (bytes + 255) & ~(size_t)255;
    return p;
  };
  unsigned short* wt   = (unsigned short*)alloc((size_t)4 * DM * DM * 2);  // 2 MB
  unsigned short* qq   = (unsigned short*)alloc((size_t)BH * S * HD * 2);  // 4 MB
  unsigned short* kk2  = (unsigned short*)alloc((size_t)BH * S * HD * 2);  // 4 MB
  unsigned short* vstd = (unsigned short*)alloc((size_t)BH * S * HD * 2);  // 4 MB
  unsigned short* vvT  = (unsigned short*)alloc((size_t)BH * S * HD * 2);  // 4 MB
  float*          invZ = (float*)alloc((size_t)BH * S * 4);                // 128 KB
  unsigned short* conc = (unsigned short*)alloc((size_t)MROWS * DM * 2);   // 4 MB

  float* out_final = (float*)d_out;
  float* out_attn  = (float*)d_out + (size_t)MROWS * DM;

  k_wtrans<<<dim3(8, 8, 4), dim3(64, 4), 0, stream>>>(wq_w, wk_w, wv_w, wo_w, wt);
  k_proj<<<dim3(64, 8, 3), 256, 0, stream>>>(q, k, v, wt, wq_b, wk_b, wv_b, qq, kk2, vstd);
  k_vtrans<<<dim3(32, 16), dim3(64, 4), 0, stream>>>(vstd, vvT);
  k_softmax_z<<<dim3(32, 16), 256, 0, stream>>>(qq, kk2, mask, invZ);
  k_attn<<<dim3(32, 16), 256, 0, stream>>>(qq, kk2, vvT, mask, invZ, out_attn, conc);
  k_outproj<<<dim3(64, 8), 256, 0, stream>>>(conc, wt, wo_b, out_final);
}